// Round 1
// baseline (1316.536 us; speedup 1.0000x reference)
//
#include <hip/hip_runtime.h>
#include <math.h>

#define SLEN 2048
#define BATCH 8
#define DMODEL 256
#define HEADS 8
#define DPROJ 128
#define DFF 1024
#define DH 16
#define MROWS (SLEN*BATCH)   // 16384
#define BK 16

// ---------------------------------------------------------------------------
// Generic tiled fp32 GEMM: C[M,N] = A[M,K] @ W[K,N] (+bias) (+relu)
// 128x128 tile, 256 threads, 8x8 micro-tile. k-major LDS, pad 129.
// Lane mapping: tx = tid&15 (cols tx+16j), ty = tid>>4 (rows ty+16i)
// -> LDS reads broadcast (A) / conflict-free consecutive banks (W).
// ---------------------------------------------------------------------------
template<bool RELU, bool HAS_BIAS>
__global__ void gemm_kernel(const float* __restrict__ A, const float* __restrict__ W,
                            const float* __restrict__ bias, float* __restrict__ C,
                            int M, int N, int K) {
    __shared__ float As[BK][129];
    __shared__ float Ws[BK][129];
    const int tid = threadIdx.x;
    const int tx = tid & 15;
    const int ty = tid >> 4;
    const int row0 = blockIdx.x * 128;
    const int col0 = blockIdx.y * 128;
    float acc[8][8] = {};
    for (int k0 = 0; k0 < K; k0 += BK) {
        #pragma unroll
        for (int i = 0; i < 8; ++i) {
            int idx = tid + i * 256;
            int rr = idx >> 4, kk = idx & 15;
            As[kk][rr] = A[(size_t)(row0 + rr) * K + k0 + kk];
        }
        #pragma unroll
        for (int i = 0; i < 8; ++i) {
            int idx = tid + i * 256;
            int kk = idx >> 7, cc = idx & 127;
            Ws[kk][cc] = W[(size_t)(k0 + kk) * N + col0 + cc];
        }
        __syncthreads();
        #pragma unroll
        for (int kk = 0; kk < BK; ++kk) {
            float av[8], wv[8];
            #pragma unroll
            for (int i = 0; i < 8; ++i) av[i] = As[kk][ty + 16 * i];
            #pragma unroll
            for (int j = 0; j < 8; ++j) wv[j] = Ws[kk][tx + 16 * j];
            #pragma unroll
            for (int i = 0; i < 8; ++i)
                #pragma unroll
                for (int j = 0; j < 8; ++j)
                    acc[i][j] += av[i] * wv[j];
        }
        __syncthreads();
    }
    float bv[8];
    #pragma unroll
    for (int j = 0; j < 8; ++j) bv[j] = HAS_BIAS ? bias[col0 + tx + 16 * j] : 0.f;
    #pragma unroll
    for (int i = 0; i < 8; ++i) {
        size_t rbase = (size_t)(row0 + ty + 16 * i) * N + col0;
        #pragma unroll
        for (int j = 0; j < 8; ++j) {
            float c = acc[i][j] + bv[j];
            if (RELU) c = fmaxf(c, 0.f);
            C[rbase + tx + 16 * j] = c;
        }
    }
}

// ---------------------------------------------------------------------------
// QKV projection: same tiling, K=256, N=128, 3 outputs via blockIdx.z,
// scatter-write into head layout qh[bh][s][dh], bh = b*8 + h.
// ---------------------------------------------------------------------------
__global__ void qkv_kernel(const float* __restrict__ src,
                           const float* __restrict__ Wq, const float* __restrict__ bq,
                           const float* __restrict__ Wk, const float* __restrict__ bk,
                           const float* __restrict__ Wv, const float* __restrict__ bv,
                           float* __restrict__ qh, float* __restrict__ kh, float* __restrict__ vh) {
    const int which = blockIdx.z;
    const float* W  = which == 0 ? Wq : (which == 1 ? Wk : Wv);
    const float* bs = which == 0 ? bq : (which == 1 ? bk : bv);
    float* out      = which == 0 ? qh : (which == 1 ? kh : vh);
    __shared__ float As[BK][129];
    __shared__ float Ws[BK][129];
    const int tid = threadIdx.x;
    const int tx = tid & 15;
    const int ty = tid >> 4;
    const int row0 = blockIdx.x * 128;
    float acc[8][8] = {};
    for (int k0 = 0; k0 < DMODEL; k0 += BK) {
        #pragma unroll
        for (int i = 0; i < 8; ++i) {
            int idx = tid + i * 256;
            int rr = idx >> 4, kk = idx & 15;
            As[kk][rr] = src[(size_t)(row0 + rr) * DMODEL + k0 + kk];
        }
        // W tile: 16 x 128
        #pragma unroll
        for (int i = 0; i < 8; ++i) {
            int idx = tid + i * 256;
            int kk = idx >> 7, cc = idx & 127;
            Ws[kk][cc] = W[(size_t)(k0 + kk) * DPROJ + cc];
        }
        __syncthreads();
        #pragma unroll
        for (int kk = 0; kk < BK; ++kk) {
            float av[8], wv[8];
            #pragma unroll
            for (int i = 0; i < 8; ++i) av[i] = As[kk][ty + 16 * i];
            #pragma unroll
            for (int j = 0; j < 8; ++j) wv[j] = Ws[kk][tx + 16 * j];
            #pragma unroll
            for (int i = 0; i < 8; ++i)
                #pragma unroll
                for (int j = 0; j < 8; ++j)
                    acc[i][j] += av[i] * wv[j];
        }
        __syncthreads();
    }
    // col = tx + 16*j  ->  h = j, d = tx
    #pragma unroll
    for (int i = 0; i < 8; ++i) {
        int r = row0 + ty + 16 * i;
        int b = r & 7, s = r >> 3;
        #pragma unroll
        for (int j = 0; j < 8; ++j) {
            float c = acc[i][j] + bs[tx + 16 * j];
            out[((size_t)(b * 8 + j) * SLEN + s) * DH + tx] = c;
        }
    }
}

// ---------------------------------------------------------------------------
// Flash attention, fp32. Grid: (32 q-tiles, 64 bh). Block 256.
// row = tid>>2 (64 q rows/tile), qt = tid&3 (k-quarter within a 64-wide k tile).
// K/V tiles in LDS as float4[64][4] with XOR-chunk swizzle (c ^ (kr>>4)) to
// break the 4-way bank conflict from the 256-float row-group stride.
// Online softmax; per-lane partial l and o over its k-quarter; final 4-lane
// shfl reduce; lane qt==0 writes the row (into row-major (S*B, 128) ctx).
// ---------------------------------------------------------------------------
__global__ void attn_kernel(const float* __restrict__ qh, const float* __restrict__ kh,
                            const float* __restrict__ vh, float* __restrict__ ctx) {
    __shared__ float4 Ks[64][4];
    __shared__ float4 Vs[64][4];
    const int bh = blockIdx.y;
    const int q0 = blockIdx.x * 64;
    const int tid = threadIdx.x;
    const int row = tid >> 2;
    const int qt = tid & 3;

    float4 q4[4];
    {
        const float4* qp = (const float4*)(qh + ((size_t)bh * SLEN + q0 + row) * DH);
        #pragma unroll
        for (int c = 0; c < 4; ++c) {
            float4 t = qp[c];
            q4[c] = make_float4(t.x * 0.25f, t.y * 0.25f, t.z * 0.25f, t.w * 0.25f);
        }
    }
    float m = -1e30f, l = 0.f;
    float4 o4[4];
    #pragma unroll
    for (int c = 0; c < 4; ++c) o4[c] = make_float4(0.f, 0.f, 0.f, 0.f);

    for (int kt = 0; kt < SLEN / 64; ++kt) {
        __syncthreads();
        {
            int kr = tid >> 2, c = tid & 3;
            int sw = c ^ ((kr >> 4) & 3);
            const float4* kp = (const float4*)(kh + ((size_t)bh * SLEN + kt * 64 + kr) * DH);
            const float4* vp = (const float4*)(vh + ((size_t)bh * SLEN + kt * 64 + kr) * DH);
            Ks[kr][sw] = kp[c];
            Vs[kr][sw] = vp[c];
        }
        __syncthreads();

        float sc[16];
        float mt = -1e30f;
        #pragma unroll
        for (int j = 0; j < 16; ++j) {
            int kr = qt * 16 + j;
            float s = 0.f;
            #pragma unroll
            for (int c = 0; c < 4; ++c) {
                float4 kv = Ks[kr][c ^ qt];
                s += q4[c].x * kv.x + q4[c].y * kv.y + q4[c].z * kv.z + q4[c].w * kv.w;
            }
            sc[j] = s;
            mt = fmaxf(mt, s);
        }
        mt = fmaxf(mt, __shfl_xor(mt, 1));
        mt = fmaxf(mt, __shfl_xor(mt, 2));
        float mn = fmaxf(m, mt);
        float alpha = __expf(m - mn);
        m = mn;
        l *= alpha;
        #pragma unroll
        for (int c = 0; c < 4; ++c) {
            o4[c].x *= alpha; o4[c].y *= alpha; o4[c].z *= alpha; o4[c].w *= alpha;
        }
        #pragma unroll
        for (int j = 0; j < 16; ++j) {
            float p = __expf(sc[j] - mn);
            l += p;
            int kr = qt * 16 + j;
            #pragma unroll
            for (int c = 0; c < 4; ++c) {
                float4 vv = Vs[kr][c ^ qt];
                o4[c].x += p * vv.x; o4[c].y += p * vv.y;
                o4[c].z += p * vv.z; o4[c].w += p * vv.w;
            }
        }
    }
    #pragma unroll
    for (int c = 0; c < 4; ++c) {
        o4[c].x += __shfl_xor(o4[c].x, 1); o4[c].x += __shfl_xor(o4[c].x, 2);
        o4[c].y += __shfl_xor(o4[c].y, 1); o4[c].y += __shfl_xor(o4[c].y, 2);
        o4[c].z += __shfl_xor(o4[c].z, 1); o4[c].z += __shfl_xor(o4[c].z, 2);
        o4[c].w += __shfl_xor(o4[c].w, 1); o4[c].w += __shfl_xor(o4[c].w, 2);
    }
    l += __shfl_xor(l, 1);
    l += __shfl_xor(l, 2);
    if (qt == 0) {
        float inv = 1.f / l;
        int s = q0 + row, b = bh >> 3, h = bh & 7;
        float* dst = ctx + ((size_t)s * BATCH + b) * DPROJ + h * DH;
        #pragma unroll
        for (int c = 0; c < 4; ++c) {
            ((float4*)dst)[c] = make_float4(o4[c].x * inv, o4[c].y * inv,
                                            o4[c].z * inv, o4[c].w * inv);
        }
    }
}

// ---------------------------------------------------------------------------
// Fused residual add + LayerNorm over D=256. One block (256 thr) per row.
// out = (v - mu) * rsqrt(var + eps) * g + b,  v = a + r
// ---------------------------------------------------------------------------
__global__ void add_ln_kernel(const float* __restrict__ a, const float* __restrict__ r,
                              const float* __restrict__ g, const float* __restrict__ bb,
                              float* __restrict__ out) {
    const int row = blockIdx.x;
    const int t = threadIdx.x;
    size_t base = (size_t)row * DMODEL;
    float v = a[base + t] + r[base + t];
    float s = v;
    #pragma unroll
    for (int off = 1; off < 64; off <<= 1) s += __shfl_xor(s, off);
    __shared__ float red1[4];
    __shared__ float red2[4];
    const int wid = t >> 6;
    if ((t & 63) == 0) red1[wid] = s;
    __syncthreads();
    float mu = (red1[0] + red1[1] + red1[2] + red1[3]) * (1.0f / 256.0f);
    float dv = v - mu;
    float s2 = dv * dv;
    #pragma unroll
    for (int off = 1; off < 64; off <<= 1) s2 += __shfl_xor(s2, off);
    if ((t & 63) == 0) red2[wid] = s2;
    __syncthreads();
    float var = (red2[0] + red2[1] + red2[2] + red2[3]) * (1.0f / 256.0f);
    float rs = rsqrtf(var + 1e-5f);
    out[base + t] = dv * rs * g[t] + bb[t];
}

// ---------------------------------------------------------------------------
extern "C" void kernel_launch(void* const* d_in, const int* in_sizes, int n_in,
                              void* d_out, int out_size, void* d_ws, size_t ws_size,
                              hipStream_t stream) {
    const float* src = (const float*)d_in[0];
    const float* Wq  = (const float*)d_in[1];
    const float* bq  = (const float*)d_in[2];
    const float* Wk  = (const float*)d_in[3];
    const float* bk  = (const float*)d_in[4];
    const float* Wv  = (const float*)d_in[5];
    const float* bv  = (const float*)d_in[6];
    const float* Wo  = (const float*)d_in[7];
    const float* g1  = (const float*)d_in[8];
    const float* be1 = (const float*)d_in[9];
    const float* W1  = (const float*)d_in[10];
    const float* b1  = (const float*)d_in[11];
    const float* W2  = (const float*)d_in[12];
    const float* b2  = (const float*)d_in[13];
    const float* g2  = (const float*)d_in[14];
    const float* be2 = (const float*)d_in[15];
    float* ws = (float*)d_ws;
    float* out = (float*)d_out;

    // workspace layout (floats), liveness-packed (~96 MB):
    //   qh 0..2M, kh 2M..4M, vh 4M..6M, ctx 6M..8M, y 8M..12M  (all dead by FFN1)
    //   h reuses 0..16M; x 16M..20M; f 20M..24M
    float* qh  = ws;
    float* kh  = ws + 2097152;
    float* vh  = ws + 4194304;
    float* ctx = ws + 6291456;
    float* y   = ws + 8388608;
    float* hb  = ws;             // 16384x1024, overlaps dead qh/kh/vh/ctx/y
    float* x   = ws + 16777216;
    float* f   = ws + 20971520;

    // 1) QKV projections -> head layout
    qkv_kernel<<<dim3(128, 1, 3), 256, 0, stream>>>(src, Wq, bq, Wk, bk, Wv, bv, qh, kh, vh);
    // 2) flash attention -> ctx in row-major (S*B, 128)
    attn_kernel<<<dim3(32, 64), 256, 0, stream>>>(qh, kh, vh, ctx);
    // 3) y = ctx @ Wo   (no bias)
    gemm_kernel<false, false><<<dim3(128, 2), 256, 0, stream>>>(ctx, Wo, nullptr, y,
                                                                MROWS, DMODEL, DPROJ);
    // 4) x = LN1(src + y)
    add_ln_kernel<<<MROWS, 256, 0, stream>>>(src, y, g1, be1, x);
    // 5) h = relu(x @ W1 + b1)
    gemm_kernel<true, true><<<dim3(128, 8), 256, 0, stream>>>(x, W1, b1, hb,
                                                              MROWS, DFF, DMODEL);
    // 6) f = h @ W2 + b2
    gemm_kernel<false, true><<<dim3(128, 2), 256, 0, stream>>>(hb, W2, b2, f,
                                                               MROWS, DMODEL, DFF);
    // 7) out = LN2(x + f)
    add_ln_kernel<<<MROWS, 256, 0, stream>>>(x, f, g2, be2, out);
}